// Round 4
// baseline (105.182 us; speedup 1.0000x reference)
//
#include <hip/hip_runtime.h>

#define BATCH 32768
#define EPB   32     // elements per 256-thread block; 8 lanes/element (same wave)
#define RS    20     // u_s row stride (floats): q*20 % 32 spreads 8 rows over 8 bank-quads
#define US    324    // u_s element stride: 16*20+4 ; 324%32=4 -> e*4 gives 8 DISJOINT b128 bank groups
#define CS    38     // cs_s element stride: 6e+2j banks distinct across e
#define XS    18     // x_s element stride: 2*(9e+i) banks distinct across e

// exp(v/1000) for |v| <~ 6 : cubic Taylor, rel err < 4e-14
__device__ __forceinline__ float pexp1k(float v) {
    float t = v * 1.0e-3f;
    return 1.0f + t * (1.0f + t * (0.5f + t * 0.16666667f));
}

__global__ __launch_bounds__(256, 3)
void dsit_kernel(const float* __restrict__ x, const float* __restrict__ h,
                 float* __restrict__ out_z, float* __restrict__ out_ld) {
    __shared__ float u_s[EPB * US];    // 41472 B
    __shared__ float cs_s[EPB * CS];   //  4864 B
    __shared__ float x_s[EPB * XS];    //  2304 B   (total 47.5 KB -> 3 blocks/CU)

    const int tid = threadIdx.x;
    const int blk = blockIdx.x;
    const int e = tid >> 3;   // element within block (8 per wave -> intra-wave, no barriers)
    const int q = tid & 7;    // lane owns rows q and q+8

    const float* hb = h + (size_t)blk * (EPB * 544) + e * 544;

    // x: coalesced float2 per lane -> LDS
    float2 xv = *(const float2*)(x + (size_t)blk * (EPB * 16) + e * 16 + 2 * q);
    *(float2*)&x_s[e * XS + 2 * q] = xv;

    float daA = hb[q],      daB = hb[q + 8];
    float dbA = hb[16 + q], dbB = hb[24 + q];

    // own rows q, q+8 of w and u: 4x dwordx4 each (64B rows, lanes q=0..7 contiguous 512B)
    float uA[16], uB[16], wA[16], wB[16];
    #pragma unroll
    for (int k = 0; k < 4; ++k) {
        *(float4*)&uA[4 * k] = *(const float4*)(hb + 288 + 16 * q + 4 * k);
        *(float4*)&uB[4 * k] = *(const float4*)(hb + 288 + 16 * (q + 8) + 4 * k);
        *(float4*)&wA[4 * k] = *(const float4*)(hb + 32 + 16 * q + 4 * k);
        *(float4*)&wB[4 * k] = *(const float4*)(hb + 32 + 16 * (q + 8) + 4 * k);
    }

    // u softmax (both rows)
    float sA = 0.f, sB = 0.f;
    #pragma unroll
    for (int i = 0; i < 16; ++i) {
        uA[i] = pexp1k(uA[i]); sA += uA[i];
        uB[i] = pexp1k(uB[i]); sB += uB[i];
    }
    float uinvA = 1.0f / sA, uinvB = 1.0f / sB;

    // ux dots: read x back as float2 broadcasts (conflict-free), reuse for both rows
    float dotA = 0.f, dotB = 0.f;
    #pragma unroll
    for (int i2 = 0; i2 < 8; ++i2) {
        float2 xx = *(const float2*)&x_s[e * XS + 2 * i2];
        dotA = fmaf(uA[2 * i2], xx.x, fmaf(uA[2 * i2 + 1], xx.y, dotA));
        dotB = fmaf(uB[2 * i2], xx.x, fmaf(uB[2 * i2 + 1], xx.y, dotB));
    }
    float uxA = dotA * uinvA, uxB = dotB * uinvB;

    // publish normalized u rows (b128; 8-phase floor, no excess conflicts)
    #pragma unroll
    for (int k = 0; k < 4; ++k) {
        float4 ta = make_float4(uA[4*k] * uinvA, uA[4*k+1] * uinvA,
                                uA[4*k+2] * uinvA, uA[4*k+3] * uinvA);
        float4 tb = make_float4(uB[4*k] * uinvB, uB[4*k+1] * uinvB,
                                uB[4*k+2] * uinvB, uB[4*k+3] * uinvB);
        *(float4*)&u_s[e * US + q * RS + 4 * k]       = ta;
        *(float4*)&u_s[e * US + (q + 8) * RS + 4 * k] = tb;
    }

    // w softmax (both rows)
    float twA = 0.f, twB = 0.f;
    #pragma unroll
    for (int j = 0; j < 16; ++j) {
        wA[j] = pexp1k(wA[j]); twA += wA[j];
        wB[j] = pexp1k(wB[j]); twB += wB[j];
    }
    float winvA = 1.0f / twA, winvB = 1.0f / twB;
    #pragma unroll
    for (int j = 0; j < 16; ++j) { wA[j] *= winvA; wB[j] *= winvB; }

    // a = softplus(U_A + da/1000) + 1e-3 (quadratic expansion, err ~1e-9); b = db/1000
    float taA = daA * 1.0e-3f, taB = daB * 1.0e-3f;
    float aA = 1.0006320f + taA * (0.6319822f + 0.1162903f * taA);
    float aB = 1.0006320f + taB * (0.6319822f + 0.1162903f * taB);
    float bbA = dbA * 1.0e-3f, bbB = dbB * 1.0e-3f;

    // c = sigmoid(a*ux+b); s = sig(c)*(1-sig(c))*a ; publish (c,s) pairs
    float cA = 1.0f / (1.0f + __expf(-fmaf(aA, uxA, bbA)));
    float cB = 1.0f / (1.0f + __expf(-fmaf(aB, uxB, bbB)));
    float scA = 1.0f / (1.0f + __expf(-cA));
    float scB = 1.0f / (1.0f + __expf(-cB));
    float ssA = scA * (1.0f - scA) * aA;
    float ssB = scB * (1.0f - scB) * aB;
    *(float2*)&cs_s[e * CS + 2 * q]        = make_float2(cA, ssA);
    *(float2*)&cs_s[e * CS + 2 * (q + 8)]  = make_float2(cB, ssB);
    // intra-wave DS ordering: no barrier needed

    // d = w @ c ; fold s into w rows
    float dA = 0.f, dB = 0.f;
    #pragma unroll
    for (int j = 0; j < 16; ++j) {
        float2 cs = *(const float2*)&cs_s[e * CS + 2 * j];
        dA = fmaf(wA[j], cs.x, dA);
        dB = fmaf(wB[j], cs.x, dB);
        wA[j] *= cs.y; wB[j] *= cs.y;
    }
    float zA = __logf(dA / (1.0f - dA));
    float zB = __logf(dB / (1.0f - dB));
    size_t zb = (size_t)blk * (EPB * 16) + e * 16;
    out_z[zb + q]     = zA;
    out_z[zb + q + 8] = zB;

    // M[row][i] = sum_j ws[row][j]*u[j][i]; logs via grouped products of 8
    // (entries ~0.0147 -> prod8 ~ 1e-15..1e-11, safely normal fp32)
    float part = 16.0f * (zA + zB);
    float prodA = 1.0f, prodB = 1.0f;
    #pragma unroll
    for (int i4 = 0; i4 < 4; ++i4) {
        float a0=0.f,a1=0.f,a2=0.f,a3=0.f, b0=0.f,b1=0.f,b2=0.f,b3=0.f;
        #pragma unroll
        for (int j = 0; j < 16; ++j) {
            float4 uq = *(const float4*)&u_s[e * US + j * RS + (i4 << 2)];
            float wa = wA[j], wb = wB[j];
            a0 = fmaf(wa, uq.x, a0); a1 = fmaf(wa, uq.y, a1);
            a2 = fmaf(wa, uq.z, a2); a3 = fmaf(wa, uq.w, a3);
            b0 = fmaf(wb, uq.x, b0); b1 = fmaf(wb, uq.y, b1);
            b2 = fmaf(wb, uq.z, b2); b3 = fmaf(wb, uq.w, b3);
        }
        prodA *= (a0 * a1) * (a2 * a3);
        prodB *= (b0 * b1) * (b2 * b3);
        if (i4 == 1) {
            part += __logf(prodA) + __logf(prodB);
            prodA = 1.0f; prodB = 1.0f;
        }
    }
    part += __logf(prodA) + __logf(prodB);

    // 8-lane reduction -> log_det
    #pragma unroll
    for (int m = 1; m < 8; m <<= 1) part += __shfl_xor(part, m, 8);
    if (q == 0) out_ld[blk * EPB + e] = part;
}

extern "C" void kernel_launch(void* const* d_in, const int* in_sizes, int n_in,
                              void* d_out, int out_size, void* d_ws, size_t ws_size,
                              hipStream_t stream) {
    const float* x = (const float*)d_in[0];
    const float* h = (const float*)d_in[1];
    float* out_z  = (float*)d_out;
    float* out_ld = out_z + (size_t)BATCH * 16;

    dsit_kernel<<<dim3(BATCH / EPB), dim3(256), 0, stream>>>(x, h, out_z, out_ld);
}

// Round 5
// 100.965 us; speedup vs baseline: 1.0418x; 1.0418x over previous
//
#include <hip/hip_runtime.h>

#define BATCH 32768
#define EPB   16     // elements per 256-thread block; 16 lanes per element (same wave)
#define RS    20     // u_s row stride (floats)
#define US    328    // u_s element stride: 16*20+8 (mod 32 = 8 -> 4 distinct bank groups/wave)
#define CS    40     // cs_s element stride (floats): 16 float2 + 8 pad

// exp(v/1000) for |v| <~ 6 : cubic Taylor, rel err < 4e-14 (better than expf here)
__device__ __forceinline__ float pexp1k(float v) {
    float t = v * 1.0e-3f;
    return 1.0f + t * (1.0f + t * (0.5f + t * 0.16666667f));
}

__global__ __launch_bounds__(256, 6)   // 85-VGPR cap -> 24 waves/CU; LDS 24.8KB*6 = 149KB fits
void dsit_kernel(const float* __restrict__ x, const float* __restrict__ h,
                 float* __restrict__ out_z, float* __restrict__ out_ld) {
    __shared__ float u_s[EPB * US];    // 20992 B, wave-private regions -> no barriers
    __shared__ float cs_s[EPB * CS];   //  2560 B

    const int tid = threadIdx.x;
    const int blk = blockIdx.x;
    const int e = tid >> 4;
    const int r = tid & 15;

    const float* hb = h + (size_t)blk * (EPB * 544) + e * 544;

    // per-lane x: lane (e,r) holds x[e][r] (fully coalesced dword)
    float x_val = x[(size_t)blk * 256 + tid];
    float da = hb[r];
    float db = hb[16 + r];

    // this lane owns row r of w and u: 4x dwordx4 each, 64B aligned rows
    float ur[16], wr[16];
    *(float4*)&ur[0]  = *(const float4*)(hb + 288 + 16 * r);
    *(float4*)&ur[4]  = *(const float4*)(hb + 288 + 16 * r + 4);
    *(float4*)&ur[8]  = *(const float4*)(hb + 288 + 16 * r + 8);
    *(float4*)&ur[12] = *(const float4*)(hb + 288 + 16 * r + 12);
    *(float4*)&wr[0]  = *(const float4*)(hb + 32 + 16 * r);
    *(float4*)&wr[4]  = *(const float4*)(hb + 32 + 16 * r + 4);
    *(float4*)&wr[8]  = *(const float4*)(hb + 32 + 16 * r + 8);
    *(float4*)&wr[12] = *(const float4*)(hb + 32 + 16 * r + 12);

    // u row softmax via polynomial exp
    float usum = 0.0f;
    #pragma unroll
    for (int i = 0; i < 16; ++i) { ur[i] = pexp1k(ur[i]); usum += ur[i]; }
    float uinv = 1.0f / usum;

    // ux = sum_i u[i]*x[e][i] via width-16 shuffles (no LDS, no barrier)
    float dot = 0.0f;
    #pragma unroll
    for (int i = 0; i < 16; ++i) dot += ur[i] * __shfl(x_val, i, 16);
    float ux = uinv * dot;

    // publish normalized u row (b128 writes; 4 e-groups -> 4 disjoint bank quads)
    #pragma unroll
    for (int q = 0; q < 4; ++q) {
        float4 t = make_float4(ur[4*q] * uinv, ur[4*q+1] * uinv,
                               ur[4*q+2] * uinv, ur[4*q+3] * uinv);
        *(float4*)&u_s[e * US + r * RS + 4 * q] = t;
    }

    // w row softmax
    float wsum = 0.0f;
    #pragma unroll
    for (int j = 0; j < 16; ++j) { wr[j] = pexp1k(wr[j]); wsum += wr[j]; }
    float winv = 1.0f / wsum;
    #pragma unroll
    for (int j = 0; j < 16; ++j) wr[j] *= winv;

    // a = softplus(U_A + da/1000) + 1e-3 : quadratic expansion around U_A (err ~1e-9)
    float ta = da * 1.0e-3f;
    float a  = 1.0006320f + ta * (0.6319822f + 0.1162903f * ta);
    float bb = db * 1.0e-3f;

    // c = sigmoid(a*ux + b); s = sigmoid(c)*(1-sigmoid(c))*a
    float cpre = fmaf(a, ux, bb);
    float c  = 1.0f / (1.0f + __expf(-cpre));
    float sc = 1.0f / (1.0f + __expf(-c));
    float s  = sc * (1.0f - sc) * a;
    *(float2*)&cs_s[e * CS + 2 * r] = make_float2(c, s);
    // intra-wave LDS exchange: DS pipe is in-order within a wave -> no barrier

    // d = w @ c ; fold s into w (ws[j] = w[r][j]*s[j])
    float d = 0.0f;
    #pragma unroll
    for (int j = 0; j < 16; ++j) {
        float2 cs = *(const float2*)&cs_s[e * CS + 2 * j];
        d = fmaf(wr[j], cs.x, d);
        wr[j] *= cs.y;
    }
    float z = __logf(d / (1.0f - d));
    out_z[(size_t)blk * 256 + tid] = z;   // fully coalesced

    // M[r][i] = sum_j ws[j]*u[j][i]; sum_i log M via two grouped products of 8
    // (M entries ~0.0147 -> prod8 ~1e-15, safely normal fp32)
    float part = 16.0f * z;
    float prod = 1.0f;
    #pragma unroll
    for (int i4 = 0; i4 < 4; ++i4) {
        float ax = 0.f, ay = 0.f, az = 0.f, aw = 0.f;
        #pragma unroll
        for (int j = 0; j < 16; ++j) {
            float wj = wr[j];
            float4 uq = *(const float4*)&u_s[e * US + j * RS + (i4 << 2)];
            ax = fmaf(wj, uq.x, ax); ay = fmaf(wj, uq.y, ay);
            az = fmaf(wj, uq.z, az); aw = fmaf(wj, uq.w, aw);
        }
        prod *= (ax * ay) * (az * aw);
        if (i4 == 1) { part += __logf(prod); prod = 1.0f; }
    }
    part += __logf(prod);

    #pragma unroll
    for (int m = 1; m < 16; m <<= 1) part += __shfl_xor(part, m, 16);
    if (r == 0) out_ld[blk * EPB + e] = part;
}

extern "C" void kernel_launch(void* const* d_in, const int* in_sizes, int n_in,
                              void* d_out, int out_size, void* d_ws, size_t ws_size,
                              hipStream_t stream) {
    const float* x = (const float*)d_in[0];
    const float* h = (const float*)d_in[1];
    float* out_z  = (float*)d_out;
    float* out_ld = out_z + (size_t)BATCH * 16;

    dsit_kernel<<<dim3(BATCH / EPB), dim3(256), 0, stream>>>(x, h, out_z, out_ld);
}

// Round 6
// 100.542 us; speedup vs baseline: 1.0461x; 1.0042x over previous
//
#include <hip/hip_runtime.h>

#define BATCH 32768
#define EPB   16     // elements per 256-thread block; 16 lanes per element (same wave)
#define RS    20     // u_s row stride (floats)
#define US    328    // u_s element stride: 16*20+8 (mod 32 = 8 -> 4 distinct bank groups/wave)
#define CS    40     // cs_s element stride (floats): 16 float2 + 8 pad

// exp(v/1000) for |v| <~ 6 : cubic Taylor, rel err < 4e-14 (better than expf here)
__device__ __forceinline__ float pexp1k(float v) {
    float t = v * 1.0e-3f;
    return 1.0f + t * (1.0f + t * (0.5f + t * 0.16666667f));
}

// Best-measured config: (256,4). (256,6) was neutral (R5), 2-rows/lane regressed (R4).
__global__ __launch_bounds__(256, 4)
void dsit_kernel(const float* __restrict__ x, const float* __restrict__ h,
                 float* __restrict__ out_z, float* __restrict__ out_ld) {
    __shared__ float u_s[EPB * US];    // 20992 B, wave-private regions -> no barriers
    __shared__ float cs_s[EPB * CS];   //  2560 B

    const int tid = threadIdx.x;
    const int blk = blockIdx.x;
    const int e = tid >> 4;
    const int r = tid & 15;

    const float* hb = h + (size_t)blk * (EPB * 544) + e * 544;

    // per-lane x: lane (e,r) holds x[e][r] (fully coalesced dword)
    float x_val = x[(size_t)blk * 256 + tid];
    float da = hb[r];
    float db = hb[16 + r];

    // this lane owns row r of w and u: 4x dwordx4 each, 64B aligned rows
    float ur[16], wr[16];
    *(float4*)&ur[0]  = *(const float4*)(hb + 288 + 16 * r);
    *(float4*)&ur[4]  = *(const float4*)(hb + 288 + 16 * r + 4);
    *(float4*)&ur[8]  = *(const float4*)(hb + 288 + 16 * r + 8);
    *(float4*)&ur[12] = *(const float4*)(hb + 288 + 16 * r + 12);
    *(float4*)&wr[0]  = *(const float4*)(hb + 32 + 16 * r);
    *(float4*)&wr[4]  = *(const float4*)(hb + 32 + 16 * r + 4);
    *(float4*)&wr[8]  = *(const float4*)(hb + 32 + 16 * r + 8);
    *(float4*)&wr[12] = *(const float4*)(hb + 32 + 16 * r + 12);

    // u row softmax via polynomial exp
    float usum = 0.0f;
    #pragma unroll
    for (int i = 0; i < 16; ++i) { ur[i] = pexp1k(ur[i]); usum += ur[i]; }
    float uinv = 1.0f / usum;

    // ux = sum_i u[i]*x[e][i] via width-16 shuffles (no LDS, no barrier)
    float dot = 0.0f;
    #pragma unroll
    for (int i = 0; i < 16; ++i) dot += ur[i] * __shfl(x_val, i, 16);
    float ux = uinv * dot;

    // publish normalized u row (b128 writes; 4 e-groups -> 4 disjoint bank quads)
    #pragma unroll
    for (int q = 0; q < 4; ++q) {
        float4 t = make_float4(ur[4*q] * uinv, ur[4*q+1] * uinv,
                               ur[4*q+2] * uinv, ur[4*q+3] * uinv);
        *(float4*)&u_s[e * US + r * RS + 4 * q] = t;
    }

    // w row softmax
    float wsum = 0.0f;
    #pragma unroll
    for (int j = 0; j < 16; ++j) { wr[j] = pexp1k(wr[j]); wsum += wr[j]; }
    float winv = 1.0f / wsum;
    #pragma unroll
    for (int j = 0; j < 16; ++j) wr[j] *= winv;

    // a = softplus(U_A + da/1000) + 1e-3 : quadratic expansion around U_A (err ~1e-9)
    float ta = da * 1.0e-3f;
    float a  = 1.0006320f + ta * (0.6319822f + 0.1162903f * ta);
    float bb = db * 1.0e-3f;

    // c = sigmoid(a*ux + b); s = sigmoid(c)*(1-sigmoid(c))*a
    float cpre = fmaf(a, ux, bb);
    float c  = 1.0f / (1.0f + __expf(-cpre));
    float sc = 1.0f / (1.0f + __expf(-c));
    float s  = sc * (1.0f - sc) * a;
    *(float2*)&cs_s[e * CS + 2 * r] = make_float2(c, s);
    // intra-wave LDS exchange: DS pipe is in-order within a wave -> no barrier

    // d = w @ c ; fold s into w (ws[j] = w[r][j]*s[j])
    float d = 0.0f;
    #pragma unroll
    for (int j = 0; j < 16; ++j) {
        float2 cs = *(const float2*)&cs_s[e * CS + 2 * j];
        d = fmaf(wr[j], cs.x, d);
        wr[j] *= cs.y;
    }
    float z = __logf(d / (1.0f - d));
    out_z[(size_t)blk * 256 + tid] = z;   // fully coalesced

    // M[r][i] = sum_j ws[j]*u[j][i]; sum_i log M via two grouped products of 8
    // (M entries ~0.0147 -> prod8 ~1e-15, safely normal fp32)
    float part = 16.0f * z;
    float prod = 1.0f;
    #pragma unroll
    for (int i4 = 0; i4 < 4; ++i4) {
        float ax = 0.f, ay = 0.f, az = 0.f, aw = 0.f;
        #pragma unroll
        for (int j = 0; j < 16; ++j) {
            float wj = wr[j];
            float4 uq = *(const float4*)&u_s[e * US + j * RS + (i4 << 2)];
            ax = fmaf(wj, uq.x, ax); ay = fmaf(wj, uq.y, ay);
            az = fmaf(wj, uq.z, az); aw = fmaf(wj, uq.w, aw);
        }
        prod *= (ax * ay) * (az * aw);
        if (i4 == 1) { part += __logf(prod); prod = 1.0f; }
    }
    part += __logf(prod);

    #pragma unroll
    for (int m = 1; m < 16; m <<= 1) part += __shfl_xor(part, m, 16);
    if (r == 0) out_ld[blk * EPB + e] = part;
}

extern "C" void kernel_launch(void* const* d_in, const int* in_sizes, int n_in,
                              void* d_out, int out_size, void* d_ws, size_t ws_size,
                              hipStream_t stream) {
    const float* x = (const float*)d_in[0];
    const float* h = (const float*)d_in[1];
    float* out_z  = (float*)d_out;
    float* out_ld = out_z + (size_t)BATCH * 16;

    dsit_kernel<<<dim3(BATCH / EPB), dim3(256), 0, stream>>>(x, h, out_z, out_ld);
}